// Round 3
// baseline (791.344 us; speedup 1.0000x reference)
//
#include <hip/hip_runtime.h>
#include <hip/hip_bf16.h>

// Problem constants (fixed by the reference)
#define Hd   1024
#define Bd   32
#define Nd   20
#define Kd   10
#define NKd  200   // N*K support rows per batch
#define NKP  208   // padded to 13 * 16
#define Qd   2048
#define BM   64    // query rows per block
#define BK   32    // K-slab per MFMA step
#define ZLD  209   // z-buffer LDS row stride (208 + 1)
#define EPSf 1e-5f
#define TAU  0.02f // top-2 gap below which we refine in fp64
#define MAXF 2048

typedef __attribute__((ext_vector_type(8))) short bf16x8;
typedef __attribute__((ext_vector_type(4))) float f32x4;

static __device__ __forceinline__ unsigned short f2bf(float f) {
  union { float f; unsigned u; } c; c.f = f;
  unsigned r = c.u + 0x7FFFu + ((c.u >> 16) & 1u);  // RNE
  return (unsigned short)(r >> 16);
}
static __device__ __forceinline__ float bf2f(unsigned short h) {
  union { unsigned u; float f; } c; c.u = ((unsigned)h) << 16;
  return c.f;
}

// ---- LayerNorm support -> split bf16 (hi, lo) planes padded to NKP rows/batch,
//      plus per-row scalars G = sum(gamma*sn), Bt = sum(beta*sn). One wave/row.
__global__ __launch_bounds__(256) void ln_support(const float* __restrict__ x,
                                                  const float* __restrict__ gamma,
                                                  const float* __restrict__ beta,
                                                  unsigned short* __restrict__ y_hi,
                                                  unsigned short* __restrict__ y_lo,
                                                  float* __restrict__ Gv,
                                                  float* __restrict__ Bv) {
  int wave = threadIdx.x >> 6, lane = threadIdx.x & 63;
  int p = blockIdx.x * 4 + wave;          // padded row id in [0, Bd*NKP)
  int b = p / NKP, rr = p % NKP;
  ushort4* yh = (ushort4*)(y_hi + (size_t)p * Hd);
  ushort4* yl = (ushort4*)(y_lo + (size_t)p * Hd);
  if (rr >= NKd) {                         // padding row: zero-fill
    ushort4 z4; z4.x = z4.y = z4.z = z4.w = 0;
#pragma unroll
    for (int j = 0; j < 4; ++j) { yh[lane + j * 64] = z4; yl[lane + j * 64] = z4; }
    if (lane == 0) { Gv[p] = 0.f; Bv[p] = 0.f; }
    return;
  }
  const float4* xr = (const float4*)(x + ((size_t)b * NKd + rr) * Hd);
  float4 v[4];
  float s = 0.f, ss = 0.f;
#pragma unroll
  for (int j = 0; j < 4; ++j) {
    v[j] = xr[lane + j * 64];
    s  += v[j].x + v[j].y + v[j].z + v[j].w;
    ss += v[j].x * v[j].x + v[j].y * v[j].y + v[j].z * v[j].z + v[j].w * v[j].w;
  }
#pragma unroll
  for (int o = 32; o; o >>= 1) { s += __shfl_xor(s, o, 64); ss += __shfl_xor(ss, o, 64); }
  float mean = s * (1.0f / Hd);
  float rstd = rsqrtf(ss * (1.0f / Hd) - mean * mean + EPSf);
  const float4* gr = (const float4*)gamma;
  const float4* br = (const float4*)beta;
  float sg = 0.f, sb = 0.f;
#pragma unroll
  for (int j = 0; j < 4; ++j) {
    float4 g = gr[lane + j * 64], bb = br[lane + j * 64];
    float nx[4] = {(v[j].x - mean) * rstd * g.x + bb.x,
                   (v[j].y - mean) * rstd * g.y + bb.y,
                   (v[j].z - mean) * rstd * g.z + bb.z,
                   (v[j].w - mean) * rstd * g.w + bb.w};
    sg += nx[0] * g.x + nx[1] * g.y + nx[2] * g.z + nx[3] * g.w;
    sb += nx[0] * bb.x + nx[1] * bb.y + nx[2] * bb.z + nx[3] * bb.w;
    ushort4 ph, pl;
    ph.x = f2bf(nx[0]); pl.x = f2bf(nx[0] - bf2f(ph.x));
    ph.y = f2bf(nx[1]); pl.y = f2bf(nx[1] - bf2f(ph.y));
    ph.z = f2bf(nx[2]); pl.z = f2bf(nx[2] - bf2f(ph.z));
    ph.w = f2bf(nx[3]); pl.w = f2bf(nx[3] - bf2f(ph.w));
    yh[lane + j * 64] = ph;
    yl[lane + j * 64] = pl;
  }
#pragma unroll
  for (int o = 32; o; o >>= 1) { sg += __shfl_xor(sg, o, 64); sb += __shfl_xor(sb, o, 64); }
  if (lane == 0) { Gv[p] = sg; Bv[p] = sb; }
}

// ---- fused GEMM + stats + group-max/min/argmax. No K-loop LDS, no K-loop barriers.
// z[q][s] = rstd_q * D - mean_q * rstd_q * G[s] + Bt[s],  D = (x .* gamma) . sn
// grid: (Qd/BM, Bd), block 256 (4 waves). Wave w owns query rows [w*16, w*16+16).
__global__ __launch_bounds__(256, 3) void gemm_reduce(
    const float* __restrict__ query,
    const unsigned short* __restrict__ s_hi, const unsigned short* __restrict__ s_lo,
    const float* __restrict__ gamma,
    const float* __restrict__ Gv, const float* __restrict__ Bv,
    float* __restrict__ out_logits, float* __restrict__ out_pred,
    int* __restrict__ flag_cnt, int* __restrict__ flag_list) {
  __shared__ float zbuf[BM][ZLD];     // 53.5 KB
  __shared__ float qstat[4][16][2];   // 512 B

  int b = blockIdx.y;
  int m0 = blockIdx.x * BM;
  int t = threadIdx.x;
  int wave = t >> 6, lane = t & 63;
  int m = lane & 15, quad = lane >> 4;

  const size_t qrow0 = (size_t)b * Qd + m0;
  const float* qptr = query + (qrow0 + wave * 16 + m) * Hd;   // this lane's A row
  const unsigned short* sbh = s_hi + (size_t)b * NKP * Hd + (size_t)m * Hd;
  const unsigned short* sbl = s_lo + (size_t)b * NKP * Hd + (size_t)m * Hd;

  f32x4 acc[13];
#pragma unroll
  for (int i = 0; i < 13; ++i) acc[i] = (f32x4){0.f, 0.f, 0.f, 0.f};
  float sx = 0.f, sxx = 0.f;

  for (int kk = 0; kk < Hd; kk += BK) {
    int ko = kk + quad * 8;
    const float4* qp = (const float4*)(qptr + ko);
    float4 x0 = qp[0], x1 = qp[1];
    const float4* gp = (const float4*)(gamma + ko);
    float4 g0 = gp[0], g1 = gp[1];
    float xs[8] = {x0.x, x0.y, x0.z, x0.w, x1.x, x1.y, x1.z, x1.w};
    float gs[8] = {g0.x, g0.y, g0.z, g0.w, g1.x, g1.y, g1.z, g1.w};
    bf16x8 ah, al;
#pragma unroll
    for (int j = 0; j < 8; ++j) {
      sx += xs[j];
      sxx = fmaf(xs[j], xs[j], sxx);
      float u = xs[j] * gs[j];
      unsigned short h = f2bf(u);
      ah[j] = (short)h;
      al[j] = (short)f2bf(u - bf2f(h));
    }
    // B fragments straight from global (L1/L2-resident; shared by all 4 waves)
    size_t boff = (size_t)ko;
    bf16x8 bh = *(const bf16x8*)(sbh + boff);
    bf16x8 bl = *(const bf16x8*)(sbl + boff);
#pragma unroll
    for (int nt = 0; nt < 13; ++nt) {
      bf16x8 nbh, nbl;
      if (nt < 12) {
        size_t o2 = (size_t)(nt + 1) * 16 * Hd + boff;
        nbh = *(const bf16x8*)(sbh + o2);
        nbl = *(const bf16x8*)(sbl + o2);
      }
      acc[nt] = __builtin_amdgcn_mfma_f32_16x16x32_bf16(ah, bh, acc[nt], 0, 0, 0);
      acc[nt] = __builtin_amdgcn_mfma_f32_16x16x32_bf16(al, bh, acc[nt], 0, 0, 0);
      acc[nt] = __builtin_amdgcn_mfma_f32_16x16x32_bf16(ah, bl, acc[nt], 0, 0, 0);
      bh = nbh; bl = nbl;
    }
  }

  // row stats: reduce across quads (lanes m, m+16, m+32, m+48 hold same query row)
  sx  += __shfl_xor(sx, 16, 64);  sxx += __shfl_xor(sxx, 16, 64);
  sx  += __shfl_xor(sx, 32, 64);  sxx += __shfl_xor(sxx, 32, 64);
  float mean = sx * (1.0f / Hd);
  float rstd = rsqrtf(sxx * (1.0f / Hd) - mean * mean + EPSf);
  if (quad == 0) { qstat[wave][m][0] = mean; qstat[wave][m][1] = rstd; }
  __syncthreads();

  // epilogue: z = rstd*D - mean*rstd*G + Bt ; C layout: col=lane&15, row=quad*4+reg
  float Gc[13], Bc[13];
#pragma unroll
  for (int nt = 0; nt < 13; ++nt) {
    int col = b * NKP + nt * 16 + m;
    Gc[nt] = Gv[col];
    Bc[nt] = Bv[col];
  }
#pragma unroll
  for (int r = 0; r < 4; ++r) {
    int row = quad * 4 + r;
    float mn = qstat[wave][row][0], rs = qstat[wave][row][1];
    float mrs = mn * rs;
#pragma unroll
    for (int nt = 0; nt < 13; ++nt)
      zbuf[wave * 16 + row][nt * 16 + m] = rs * acc[nt][r] - mrs * Gc[nt] + Bc[nt];
  }
  __syncthreads();

  // phase 1: group maxes in-place (64 rows x 20 groups of 10) -> zbuf[row][g*10]
  for (int i = t; i < BM * Nd; i += 256) {
    int row = i / Nd, g = i - row * Nd;
    float* zp = &zbuf[row][g * Kd];
    float mx = zp[0];
#pragma unroll
    for (int j = 1; j < Kd; ++j) mx = fmaxf(mx, zp[j]);
    zp[0] = mx;
  }
  __syncthreads();

  // phase 2: min over N, concat, argmax (+top-2 gap flag), write
  if (t < BM) {
    int row = t;
    float mn = 3.4e38f, v1 = -3.4e38f, v2 = -3.4e38f;
    int best = 0;
    size_t orow = qrow0 + row;
    float* lp = out_logits + orow * (Nd + 1);
#pragma unroll
    for (int n = 0; n < Nd; ++n) {
      float v = zbuf[row][n * Kd];
      lp[n] = v;
      mn = fminf(mn, v);
      if (v > v1) { v2 = v1; v1 = v; best = n; }  // first-occurrence argmax
      else v2 = fmaxf(v2, v);
    }
    lp[Nd] = mn - 1.0f;  // strictly below min, never the argmax
    out_pred[orow] = (float)best;
    if (v1 - v2 < TAU) {
      int idx = atomicAdd(flag_cnt, 1);
      if (idx < MAXF) flag_list[idx] = (int)orow;
    }
  }
}

// ---------------- fp64 exact refinement for near-tie rows ----------------
__global__ __launch_bounds__(256) void refine_pred(
    const float* __restrict__ query, const float* __restrict__ support,
    const float* __restrict__ gamma, const float* __restrict__ beta,
    const int* __restrict__ flag_cnt, const int* __restrict__ flag_list,
    float* __restrict__ out_pred) {
  __shared__ double A[Hd];     // qn_full * gamma
  __shared__ double red[16];
  __shared__ double zbuf[NKd];
  __shared__ double gmax[Nd];
  int cnt = *flag_cnt; if (cnt > MAXF) cnt = MAXF;
  if ((int)blockIdx.x >= cnt) return;
  int qrow = flag_list[blockIdx.x];
  int b = qrow / Qd;
  int t = threadIdx.x, lane = t & 63, w = t >> 6;
  const float* qx = query + (size_t)qrow * Hd;
  float xv[4];
  double sx = 0.0, sxx = 0.0;
#pragma unroll
  for (int i = 0; i < 4; ++i) {
    xv[i] = qx[t * 4 + i];
    sx += (double)xv[i]; sxx += (double)xv[i] * (double)xv[i];
  }
#pragma unroll
  for (int o = 32; o; o >>= 1) { sx += __shfl_xor(sx, o, 64); sxx += __shfl_xor(sxx, o, 64); }
  if (lane == 0) { red[w] = sx; red[8 + w] = sxx; }
  __syncthreads();
  double m = (red[0] + red[1] + red[2] + red[3]) * (1.0 / Hd);
  double var = (red[8] + red[9] + red[10] + red[11]) * (1.0 / Hd) - m * m;
  double r = 1.0 / sqrt(var + 1e-5);
  double s1 = 0.0, s2 = 0.0;
#pragma unroll
  for (int i = 0; i < 4; ++i) {
    int j = t * 4 + i;
    double g = (double)gamma[j], be = (double)beta[j];
    double qn = ((double)xv[i] - m) * r * g + be;
    double a = qn * g;
    A[j] = a; s1 += a; s2 += qn * be;
  }
#pragma unroll
  for (int o = 32; o; o >>= 1) { s1 += __shfl_xor(s1, o, 64); s2 += __shfl_xor(s2, o, 64); }
  __syncthreads();
  if (lane == 0) { red[w] = s1; red[8 + w] = s2; }
  __syncthreads();
  double S1 = red[0] + red[1] + red[2] + red[3];
  double S2 = red[8] + red[9] + red[10] + red[11];
  const float* sbase = support + (size_t)b * NKd * Hd;
  for (int row = w; row < NKd; row += 4) {
    const float* xr = sbase + (size_t)row * Hd;
    double tx = 0.0, txx = 0.0, tax = 0.0;
#pragma unroll
    for (int i = 0; i < 16; ++i) {
      int j = lane + i * 64;
      double x = (double)xr[j];
      tx += x; txx += x * x; tax += A[j] * x;
    }
#pragma unroll
    for (int o = 32; o; o >>= 1) {
      tx += __shfl_xor(tx, o, 64); txx += __shfl_xor(txx, o, 64); tax += __shfl_xor(tax, o, 64);
    }
    if (lane == 0) {
      double mm = tx * (1.0 / Hd);
      double vv = txx * (1.0 / Hd) - mm * mm;
      double rr = 1.0 / sqrt(vv + 1e-5);
      zbuf[row] = rr * (tax - mm * S1) + S2;
    }
  }
  __syncthreads();
  if (t < Nd) {
    double mx = zbuf[t * Kd];
#pragma unroll
    for (int j = 1; j < Kd; ++j) mx = fmax(mx, zbuf[t * Kd + j]);
    gmax[t] = mx;
  }
  __syncthreads();
  if (t == 0) {
    double bv = gmax[0]; int best = 0;
#pragma unroll
    for (int n = 1; n < Nd; ++n) if (gmax[n] > bv) { bv = gmax[n]; best = n; }
    out_pred[qrow] = (float)best;
  }
}

extern "C" void kernel_launch(void* const* d_in, const int* in_sizes, int n_in,
                              void* d_out, int out_size, void* d_ws, size_t ws_size,
                              hipStream_t stream) {
  const float* support = (const float*)d_in[0];
  const float* query   = (const float*)d_in[1];
  const float* gamma   = (const float*)d_in[2];
  const float* beta    = (const float*)d_in[3];

  float* out = (float*)d_out;
  float* out_logits = out;                                  // 32*2048*21
  float* out_pred   = out + (size_t)Bd * Qd * (Nd + 1);     // 32*2048

  const size_t plane = (size_t)Bd * NKP * Hd;               // padded planes
  unsigned short* s_hi = (unsigned short*)d_ws;             // 13.6 MB
  unsigned short* s_lo = s_hi + plane;                      // 13.6 MB
  char* p = (char*)(s_lo + plane);
  float* Gv = (float*)p;            p += (size_t)Bd * NKP * sizeof(float);
  float* Bv = (float*)p;            p += (size_t)Bd * NKP * sizeof(float);
  int* flag_cnt = (int*)p;
  int* flag_list = (int*)(p + 256);

  hipMemsetAsync(flag_cnt, 0, sizeof(int), stream);
  ln_support<<<(Bd * NKP) / 4, 256, 0, stream>>>(support, gamma, beta, s_hi, s_lo, Gv, Bv);
  gemm_reduce<<<dim3(Qd / BM, Bd), 256, 0, stream>>>(query, s_hi, s_lo, gamma, Gv, Bv,
                                                     out_logits, out_pred, flag_cnt, flag_list);
  refine_pred<<<MAXF, 256, 0, stream>>>(query, support, gamma, beta, flag_cnt, flag_list, out_pred);
}

// Round 4
// 552.834 us; speedup vs baseline: 1.4314x; 1.4314x over previous
//
#include <hip/hip_runtime.h>
#include <hip/hip_bf16.h>

// Problem constants (fixed by the reference)
#define Hd   1024
#define Bd   32
#define Nd   20
#define Kd   10
#define NKd  200   // N*K support rows per batch
#define NKP  208   // padded to 13 * 16
#define Qd   2048
#define BM   64    // query rows per block
#define ZLD  209   // z-buffer LDS row stride
#define EPSf 1e-5f
#define TAU  0.02f // top-2 gap below which we refine in fp64
#define MAXF 2048
#define TCH  (832 * 8)   // ushorts per (batch,tile) block: 208 rows * 4 chunks * 8

typedef __attribute__((ext_vector_type(8))) short bf16x8;
typedef __attribute__((ext_vector_type(4))) float f32x4;

// swizzled ushort offset of fragment (row, k8-chunk) inside a 13312-B tile block
#define SWZ(row, k8) (((row) * 32) + (((k8) ^ ((row) & 3)) * 8))

static __device__ __forceinline__ unsigned short f2bf(float f) {
  union { float f; unsigned u; } c; c.f = f;
  unsigned r = c.u + 0x7FFFu + ((c.u >> 16) & 1u);  // RNE
  return (unsigned short)(r >> 16);
}
static __device__ __forceinline__ float bf2f(unsigned short h) {
  union { unsigned u; float f; } c; c.u = ((unsigned)h) << 16;
  return c.f;
}
static __device__ __forceinline__ void gload_lds16(const void* g, void* l) {
  __builtin_amdgcn_global_load_lds(
      (const __attribute__((address_space(1))) unsigned int*)g,
      (__attribute__((address_space(3))) unsigned int*)l, 16, 0, 0);
}

// ---- LayerNorm support -> split bf16 (hi, lo) planes in tile-major, pre-swizzled
//      layout: plane[((b*32 + T)*832 + row*4 + (k8 ^ (row&3))) * 8 ..+8].
//      Also per-row scalars G = sum(gamma*sn), Bt = sum(beta*sn). One wave/row.
__global__ __launch_bounds__(256) void ln_support(const float* __restrict__ x,
                                                  const float* __restrict__ gamma,
                                                  const float* __restrict__ beta,
                                                  unsigned short* __restrict__ y_hi,
                                                  unsigned short* __restrict__ y_lo,
                                                  float* __restrict__ Gv,
                                                  float* __restrict__ Bv) {
  int wave = threadIdx.x >> 6, lane = threadIdx.x & 63;
  int p = blockIdx.x * 4 + wave;          // padded row id in [0, Bd*NKP)
  int b = p / NKP, rr = p - b * NKP;
  int T0 = lane >> 1;                     // this lane's K-tile (2 lanes per tile)
  int k8base = (lane & 1) * 2;            // first of this lane's 2 chunks in the tile
  int sw = rr & 3;
  size_t chunkbase = (size_t)b * 32 * TCH + (size_t)T0 * TCH + (size_t)rr * 32;

  if (rr >= NKd) {                        // padding row: zero-fill
    bf16x8 z8 = {0, 0, 0, 0, 0, 0, 0, 0};
#pragma unroll
    for (int pr = 0; pr < 2; ++pr) {
      size_t off = chunkbase + (size_t)(((k8base + pr) ^ sw) * 8);
      *(bf16x8*)(y_hi + off) = z8;
      *(bf16x8*)(y_lo + off) = z8;
    }
    if (lane == 0) { Gv[p] = 0.f; Bv[p] = 0.f; }
    return;
  }
  // lane handles cols [lane*16, lane*16+16)
  const float4* xr = (const float4*)(x + ((size_t)b * NKd + rr) * Hd);
  const float4* gr = (const float4*)gamma;
  const float4* br = (const float4*)beta;
  float4 v[4];
  float s = 0.f, ss = 0.f;
#pragma unroll
  for (int j = 0; j < 4; ++j) {
    v[j] = xr[lane * 4 + j];
    s  += v[j].x + v[j].y + v[j].z + v[j].w;
    ss += v[j].x * v[j].x + v[j].y * v[j].y + v[j].z * v[j].z + v[j].w * v[j].w;
  }
#pragma unroll
  for (int o = 32; o; o >>= 1) { s += __shfl_xor(s, o, 64); ss += __shfl_xor(ss, o, 64); }
  float mean = s * (1.0f / Hd);
  float rstd = rsqrtf(ss * (1.0f / Hd) - mean * mean + EPSf);

  float nx[16];
  float sg = 0.f, sb = 0.f;
#pragma unroll
  for (int j = 0; j < 4; ++j) {
    float4 g = gr[lane * 4 + j], bb = br[lane * 4 + j];
    float xv[4] = {v[j].x, v[j].y, v[j].z, v[j].w};
    float gv4[4] = {g.x, g.y, g.z, g.w};
    float bv4[4] = {bb.x, bb.y, bb.z, bb.w};
#pragma unroll
    for (int e = 0; e < 4; ++e) {
      float n = (xv[e] - mean) * rstd * gv4[e] + bv4[e];
      nx[j * 4 + e] = n;
      sg += n * gv4[e];
      sb += n * bv4[e];
    }
  }
#pragma unroll
  for (int pr = 0; pr < 2; ++pr) {
    bf16x8 ph, pl;
#pragma unroll
    for (int e = 0; e < 8; ++e) {
      float n = nx[pr * 8 + e];
      unsigned short h = f2bf(n);
      ph[e] = (short)h;
      pl[e] = (short)f2bf(n - bf2f(h));
    }
    size_t off = chunkbase + (size_t)(((k8base + pr) ^ sw) * 8);
    *(bf16x8*)(y_hi + off) = ph;
    *(bf16x8*)(y_lo + off) = pl;
  }
#pragma unroll
  for (int o = 32; o; o >>= 1) { sg += __shfl_xor(sg, o, 64); sb += __shfl_xor(sb, o, 64); }
  if (lane == 0) { Gv[p] = sg; Bv[p] = sb; }
}

// ---- fused GEMM + stats + group-max/min/argmax.
// A per-lane registers; B double-buffered LDS via global_load_lds (pre-swizzled).
// z[q][s] = rstd_q * D - mean_q * rstd_q * G[s] + Bt[s],  D = (x .* gamma) . sn
__global__ __launch_bounds__(256, 3) void gemm_reduce(
    const float* __restrict__ query,
    const unsigned short* __restrict__ s_hi, const unsigned short* __restrict__ s_lo,
    const float* __restrict__ gamma,
    const float* __restrict__ Gv, const float* __restrict__ Bv,
    float* __restrict__ out_logits, float* __restrict__ out_pred,
    int* __restrict__ flag_cnt, int* __restrict__ flag_list) {
  __shared__ union {
    unsigned short B[2][2][TCH];   // [buf][plane]: 53248 B
    float z[BM][ZLD];              // 53504 B
  } sm;
  __shared__ float qstat[4][16][2];

  // XCD-locality decode: all 32 m-tiles of a batch land on one XCD (lin % 8)
  int lin = blockIdx.x;
  int xcd = lin & 7, sl = lin >> 3;
  int b = xcd + 8 * (sl >> 5);
  int m0 = (sl & 31) * BM;
  int t = threadIdx.x;
  int wave = t >> 6, lane = t & 63;
  int m = lane & 15, quad = lane >> 4;

  const size_t qrow0 = (size_t)b * Qd + m0;
  const float* qptr = query + (qrow0 + wave * 16 + m) * Hd;
  const unsigned short* hb = s_hi + (size_t)b * 32 * TCH;
  const unsigned short* lb = s_lo + (size_t)b * 32 * TCH;

  f32x4 acc[13];
#pragma unroll
  for (int i = 0; i < 13; ++i) acc[i] = (f32x4){0.f, 0.f, 0.f, 0.f};
  float sx = 0.f, sxx = 0.f;

  // prologue: DMA tile 0 -> buf 0 (26 wave-instrs split over 4 waves)
  for (int j = wave; j < 26; j += 4) {
    int pl = j >= 13 ? 1 : 0, jj = j - pl * 13;
    const unsigned short* src = (pl ? lb : hb) + (size_t)jj * 512 + lane * 8;
    gload_lds16(src, &sm.B[0][pl][jj * 512]);
  }

  for (int T = 0; T < 32; ++T) {
    int u = T & 1;
    // ---- A fragment per-lane: load query/gamma, LN-lite (x*gamma), split hi/lo
    int ko = T * 32 + quad * 8;
    const float4* qp = (const float4*)(qptr + ko);
    float4 x0 = qp[0], x1 = qp[1];
    const float4* gp = (const float4*)(gamma + ko);
    float4 g0 = gp[0], g1 = gp[1];
    float xs[8] = {x0.x, x0.y, x0.z, x0.w, x1.x, x1.y, x1.z, x1.w};
    float gs[8] = {g0.x, g0.y, g0.z, g0.w, g1.x, g1.y, g1.z, g1.w};
    bf16x8 ah, al;
#pragma unroll
    for (int j = 0; j < 8; ++j) {
      sx += xs[j];
      sxx = fmaf(xs[j], xs[j], sxx);
      float uu = xs[j] * gs[j];
      unsigned short h = f2bf(uu);
      ah[j] = (short)h;
      al[j] = (short)f2bf(uu - bf2f(h));
    }

    __syncthreads();  // drains DMA(T); all waves done reading buf[1-u] (iter T-1)

    if (T + 1 < 32) {  // prefetch next tile into the other buffer; overlaps MFMA
      size_t toff = (size_t)(T + 1) * TCH;
      for (int j = wave; j < 26; j += 4) {
        int pl = j >= 13 ? 1 : 0, jj = j - pl * 13;
        const unsigned short* src = (pl ? lb : hb) + toff + (size_t)jj * 512 + lane * 8;
        gload_lds16(src, &sm.B[1 - u][pl][jj * 512]);
      }
    }

    const unsigned short* Bh = sm.B[u][0];
    const unsigned short* Bl = sm.B[u][1];
#pragma unroll
    for (int nt = 0; nt < 13; ++nt) {
      int rw = nt * 16 + m;
      bf16x8 bh = *(const bf16x8*)&Bh[SWZ(rw, quad)];
      bf16x8 bl = *(const bf16x8*)&Bl[SWZ(rw, quad)];
      acc[nt] = __builtin_amdgcn_mfma_f32_16x16x32_bf16(ah, bh, acc[nt], 0, 0, 0);
      acc[nt] = __builtin_amdgcn_mfma_f32_16x16x32_bf16(al, bh, acc[nt], 0, 0, 0);
      acc[nt] = __builtin_amdgcn_mfma_f32_16x16x32_bf16(ah, bl, acc[nt], 0, 0, 0);
    }
  }

  // row stats: lanes m, m+16, m+32, m+48 hold the same query row
  sx  += __shfl_xor(sx, 16, 64);  sxx += __shfl_xor(sxx, 16, 64);
  sx  += __shfl_xor(sx, 32, 64);  sxx += __shfl_xor(sxx, 32, 64);
  float mean = sx * (1.0f / Hd);
  float rstd = rsqrtf(sxx * (1.0f / Hd) - mean * mean + EPSf);
  if (quad == 0) { qstat[wave][m][0] = mean; qstat[wave][m][1] = rstd; }
  __syncthreads();  // stats visible; B buffers dead -> reuse LDS as z-buffer

  // epilogue: z = rstd*D - mean*rstd*G + Bt ; C layout: col=lane&15, row=quad*4+reg
  float Gc[13], Bc[13];
#pragma unroll
  for (int nt = 0; nt < 13; ++nt) {
    int col = b * NKP + nt * 16 + m;
    Gc[nt] = Gv[col];
    Bc[nt] = Bv[col];
  }
#pragma unroll
  for (int r = 0; r < 4; ++r) {
    int row = quad * 4 + r;
    float mn = qstat[wave][row][0], rs = qstat[wave][row][1];
    float mrs = mn * rs;
#pragma unroll
    for (int nt = 0; nt < 13; ++nt)
      sm.z[wave * 16 + row][nt * 16 + m] = rs * acc[nt][r] - mrs * Gc[nt] + Bc[nt];
  }
  __syncthreads();

  // phase 1: group maxes in-place (64 rows x 20 groups of 10)
  for (int i = t; i < BM * Nd; i += 256) {
    int row = i / Nd, g = i - row * Nd;
    float* zp = &sm.z[row][g * Kd];
    float mx = zp[0];
#pragma unroll
    for (int j = 1; j < Kd; ++j) mx = fmaxf(mx, zp[j]);
    zp[0] = mx;
  }
  __syncthreads();

  // phase 2: min over N, concat, argmax (+top-2 gap flag), write
  if (t < BM) {
    int row = t;
    float mn = 3.4e38f, v1 = -3.4e38f, v2 = -3.4e38f;
    int best = 0;
    size_t orow = qrow0 + row;
    float* lp = out_logits + orow * (Nd + 1);
#pragma unroll
    for (int n = 0; n < Nd; ++n) {
      float v = sm.z[row][n * Kd];
      lp[n] = v;
      mn = fminf(mn, v);
      if (v > v1) { v2 = v1; v1 = v; best = n; }  // first-occurrence argmax
      else v2 = fmaxf(v2, v);
    }
    lp[Nd] = mn - 1.0f;  // strictly below min, never the argmax
    out_pred[orow] = (float)best;
    if (v1 - v2 < TAU) {
      int idx = atomicAdd(flag_cnt, 1);
      if (idx < MAXF) flag_list[idx] = (int)orow;
    }
  }
}

// ---------------- fp64 exact refinement for near-tie rows ----------------
__global__ __launch_bounds__(256) void refine_pred(
    const float* __restrict__ query, const float* __restrict__ support,
    const float* __restrict__ gamma, const float* __restrict__ beta,
    const int* __restrict__ flag_cnt, const int* __restrict__ flag_list,
    float* __restrict__ out_pred) {
  __shared__ double A[Hd];     // qn_full * gamma
  __shared__ double red[16];
  __shared__ double zbuf[NKd];
  __shared__ double gmax[Nd];
  int cnt = *flag_cnt; if (cnt > MAXF) cnt = MAXF;
  if ((int)blockIdx.x >= cnt) return;
  int qrow = flag_list[blockIdx.x];
  int b = qrow / Qd;
  int t = threadIdx.x, lane = t & 63, w = t >> 6;
  const float* qx = query + (size_t)qrow * Hd;
  float xv[4];
  double sx = 0.0, sxx = 0.0;
#pragma unroll
  for (int i = 0; i < 4; ++i) {
    xv[i] = qx[t * 4 + i];
    sx += (double)xv[i]; sxx += (double)xv[i] * (double)xv[i];
  }
#pragma unroll
  for (int o = 32; o; o >>= 1) { sx += __shfl_xor(sx, o, 64); sxx += __shfl_xor(sxx, o, 64); }
  if (lane == 0) { red[w] = sx; red[8 + w] = sxx; }
  __syncthreads();
  double m = (red[0] + red[1] + red[2] + red[3]) * (1.0 / Hd);
  double var = (red[8] + red[9] + red[10] + red[11]) * (1.0 / Hd) - m * m;
  double r = 1.0 / sqrt(var + 1e-5);
  double s1 = 0.0, s2 = 0.0;
#pragma unroll
  for (int i = 0; i < 4; ++i) {
    int j = t * 4 + i;
    double g = (double)gamma[j], be = (double)beta[j];
    double qn = ((double)xv[i] - m) * r * g + be;
    double a = qn * g;
    A[j] = a; s1 += a; s2 += qn * be;
  }
#pragma unroll
  for (int o = 32; o; o >>= 1) { s1 += __shfl_xor(s1, o, 64); s2 += __shfl_xor(s2, o, 64); }
  __syncthreads();
  if (lane == 0) { red[w] = s1; red[8 + w] = s2; }
  __syncthreads();
  double S1 = red[0] + red[1] + red[2] + red[3];
  double S2 = red[8] + red[9] + red[10] + red[11];
  const float* sbase = support + (size_t)b * NKd * Hd;
  for (int row = w; row < NKd; row += 4) {
    const float* xr = sbase + (size_t)row * Hd;
    double tx = 0.0, txx = 0.0, tax = 0.0;
#pragma unroll
    for (int i = 0; i < 16; ++i) {
      int j = lane + i * 64;
      double x = (double)xr[j];
      tx += x; txx += x * x; tax += A[j] * x;
    }
#pragma unroll
    for (int o = 32; o; o >>= 1) {
      tx += __shfl_xor(tx, o, 64); txx += __shfl_xor(txx, o, 64); tax += __shfl_xor(tax, o, 64);
    }
    if (lane == 0) {
      double mm = tx * (1.0 / Hd);
      double vv = txx * (1.0 / Hd) - mm * mm;
      double rr = 1.0 / sqrt(vv + 1e-5);
      zbuf[row] = rr * (tax - mm * S1) + S2;
    }
  }
  __syncthreads();
  if (t < Nd) {
    double mx = zbuf[t * Kd];
#pragma unroll
    for (int j = 1; j < Kd; ++j) mx = fmax(mx, zbuf[t * Kd + j]);
    gmax[t] = mx;
  }
  __syncthreads();
  if (t == 0) {
    double bv = gmax[0]; int best = 0;
#pragma unroll
    for (int n = 1; n < Nd; ++n) if (gmax[n] > bv) { bv = gmax[n]; best = n; }
    out_pred[qrow] = (float)best;
  }
}

extern "C" void kernel_launch(void* const* d_in, const int* in_sizes, int n_in,
                              void* d_out, int out_size, void* d_ws, size_t ws_size,
                              hipStream_t stream) {
  const float* support = (const float*)d_in[0];
  const float* query   = (const float*)d_in[1];
  const float* gamma   = (const float*)d_in[2];
  const float* beta    = (const float*)d_in[3];

  float* out = (float*)d_out;
  float* out_logits = out;                                  // 32*2048*21
  float* out_pred   = out + (size_t)Bd * Qd * (Nd + 1);     // 32*2048

  const size_t plane = (size_t)Bd * 32 * TCH;               // == Bd*NKP*Hd elems
  unsigned short* s_hi = (unsigned short*)d_ws;             // 13.6 MB
  unsigned short* s_lo = s_hi + plane;                      // 13.6 MB
  char* p = (char*)(s_lo + plane);
  float* Gv = (float*)p;            p += (size_t)Bd * NKP * sizeof(float);
  float* Bv = (float*)p;            p += (size_t)Bd * NKP * sizeof(float);
  int* flag_cnt = (int*)p;
  int* flag_list = (int*)(p + 256);

  hipMemsetAsync(flag_cnt, 0, sizeof(int), stream);
  ln_support<<<(Bd * NKP) / 4, 256, 0, stream>>>(support, gamma, beta, s_hi, s_lo, Gv, Bv);
  gemm_reduce<<<Qd / BM * Bd, 256, 0, stream>>>(query, s_hi, s_lo, gamma, Gv, Bv,
                                                out_logits, out_pred, flag_cnt, flag_list);
  refine_pred<<<MAXF, 256, 0, stream>>>(query, support, gamma, beta, flag_cnt, flag_list, out_pred);
}